// Round 21
// baseline (147.768 us; speedup 1.0000x reference)
//
#include <hip/hip_runtime.h>

#define B_N 32
#define S_N 1024

typedef __attribute__((ext_vector_type(8))) short sh8;
typedef __attribute__((ext_vector_type(4))) short sh4;
typedef __attribute__((ext_vector_type(4))) float f4;

#define AS1 __attribute__((address_space(1)))
#define AS3 __attribute__((address_space(3)))

__device__ __forceinline__ short f2bf(float f) {
  unsigned u = __builtin_bit_cast(unsigned, f);
  u += 0x7fff + ((u >> 16) & 1);
  return (short)(u >> 16);
}
__device__ __forceinline__ float bf2f(short s) {
  unsigned u = ((unsigned)(unsigned short)s) << 16;
  return __builtin_bit_cast(float, u);
}

#if defined(__has_builtin)
#if __has_builtin(__builtin_amdgcn_mfma_f32_16x16x16bf16_1k)
#define HAVE_MFMA16 1
#endif
#endif
__device__ __forceinline__ f4 mfma16(sh4 a, sh4 b, f4 c) {
#ifdef HAVE_MFMA16
  return __builtin_amdgcn_mfma_f32_16x16x16bf16_1k(a, b, c, 0, 0, 0);
#else
  asm volatile("v_mfma_f32_16x16x16_bf16 %0, %1, %2, %0\n\ts_nop 7\n\ts_nop 7"
               : "+v"(c) : "v"(a), "v"(b));
  return c;
#endif
}

// convert 8 consecutive f32 at src to sh8, also return abs-sum
__device__ __forceinline__ sh8 cvt8(const float* src, float& s) {
  f4 x0 = *(const f4*)src;
  f4 x1 = *(const f4*)(src + 4);
  sh8 v;
#pragma unroll
  for (int i = 0; i < 4; ++i) {
    v[i] = f2bf(x0[i]);
    v[4 + i] = f2bf(x1[i]);
    s += fabsf(x0[i]) + fabsf(x1[i]);
  }
  return v;
}

// ---------- Phase 1 (MFMA): generic 128-row x 64-col projection body ----------
template <int DIN, bool MASK>
__device__ __forceinline__ void dev_proj(
    const float* __restrict__ in, const float* __restrict__ W,
    const float* __restrict__ bias, short* __restrict__ out,
    float* __restrict__ mask, int blk) {
  constexpr int NSL = DIN / 8;
  constexpr int KT = DIN / 32;
  __shared__ __align__(16) short a_t[128 * DIN];
  __shared__ __align__(16) short w_t[64 * DIN];
  const int tid = threadIdx.x;
  const int wave = tid >> 6, lane = tid & 63;
  const int col = lane & 15, grp = lane >> 4;
  const size_t r0g = (size_t)blk * 128;

#pragma unroll
  for (int t = 0; t < 128 * NSL / 256; ++t) {
    const int u = t * 256 + tid, row = u / NSL, sl = u % NSL;
    float s = 0.f;
    sh8 v = cvt8(in + (r0g + row) * DIN + sl * 8, s);
    *(sh8*)&a_t[(row * NSL + (sl ^ (row & (NSL - 1)))) * 8] = v;
    if (MASK) {
      s += __shfl_xor(s, 1); s += __shfl_xor(s, 2);
      s += __shfl_xor(s, 4); s += __shfl_xor(s, 8);
      if ((lane & 15) == 0) mask[r0g + row] = (s != 0.f) ? 1.f : 0.f;
    }
  }
#pragma unroll
  for (int t = 0; t < 64 * NSL / 256; ++t) {
    const int u = t * 256 + tid, row = u / NSL, sl = u % NSL;
    float s = 0.f;
    sh8 v = cvt8(W + (size_t)row * DIN + sl * 8, s);
    *(sh8*)&w_t[(row * NSL + (sl ^ (row & (NSL - 1)))) * 8] = v;
  }
  __syncthreads();

  const int r0 = wave * 32;
  sh8 a[2][KT];
#pragma unroll
  for (int ri = 0; ri < 2; ++ri)
#pragma unroll
    for (int t = 0; t < KT; ++t) {
      const int row = r0 + ri * 16 + col;
      a[ri][t] = *(const sh8*)&a_t[(row * NSL + ((grp + 4 * t) ^ (row & (NSL - 1)))) * 8];
    }
  f4 acc[2][4];
#pragma unroll
  for (int ri = 0; ri < 2; ++ri)
#pragma unroll
    for (int jt = 0; jt < 4; ++jt) acc[ri][jt] = (f4)0.f;
#pragma unroll
  for (int jt = 0; jt < 4; ++jt) {
    const int j = jt * 16 + col;
    sh8 bw[KT];
#pragma unroll
    for (int t = 0; t < KT; ++t)
      bw[t] = *(const sh8*)&w_t[(j * NSL + ((grp + 4 * t) ^ (j & (NSL - 1)))) * 8];
#pragma unroll
    for (int ri = 0; ri < 2; ++ri)
#pragma unroll
      for (int t = 0; t < KT; ++t)
        acc[ri][jt] = __builtin_amdgcn_mfma_f32_16x16x32_bf16(a[ri][t], bw[t], acc[ri][jt], 0, 0, 0);
  }
#pragma unroll
  for (int jt = 0; jt < 4; ++jt) {
    const float bj = bias[jt * 16 + col];
#pragma unroll
    for (int ri = 0; ri < 2; ++ri)
#pragma unroll
      for (int r = 0; r < 4; ++r)
        out[(r0g + r0 + ri * 16 + grp * 4 + r) * 64 + jt * 16 + col] = f2bf(acc[ri][jt][r] + bj);
  }
}

__global__ __launch_bounds__(256) void proj_q_kernel(
    const float* __restrict__ in, const float* __restrict__ W,
    const float* __restrict__ bias, short* __restrict__ out,
    float* __restrict__ mask) {
  dev_proj<128, true>(in, W, bias, out, mask, blockIdx.x);
}

__global__ __launch_bounds__(256) void proj_ctx2_kernel(
    const float* __restrict__ in0, const float* __restrict__ W0,
    const float* __restrict__ b0, short* __restrict__ o0,
    const float* __restrict__ in1, const float* __restrict__ W1_,
    const float* __restrict__ b1_, short* __restrict__ o1, int nb) {
  const int sel = blockIdx.x >= nb;
  const int blk = sel ? (blockIdx.x - nb) : blockIdx.x;
  dev_proj<64, false>(sel ? in1 : in0, sel ? W1_ : W0, sel ? b1_ : b0,
                      sel ? o1 : o0, nullptr, blk);
}

// ---------- Phase 1 (MFMA): K projection + V (128 cols, transposed) + kmask ----------
__global__ __launch_bounds__(256) void proj_k_mfma(
    const float* __restrict__ in, const float* __restrict__ Wk, const float* __restrict__ bk_,
    const float* __restrict__ Wv, const float* __restrict__ bv_,
    short* __restrict__ kit, short* __restrict__ vt, float* __restrict__ km) {
  __shared__ __align__(16) char ulds[65536];
  short* a_t = (short*)ulds;
  short* w_t = (short*)(ulds + 32768);
  const int tid = threadIdx.x;
  const int wave = tid >> 6, lane = tid & 63;
  const int col = lane & 15, grp = lane >> 4;
  const size_t r0g = (size_t)blockIdx.x * 128;
  const int bb = (int)(r0g >> 10), s0 = (int)(r0g & 1023);

#pragma unroll
  for (int t = 0; t < 8; ++t) {
    const int u = t * 256 + tid, row = u >> 4, sl = u & 15;
    float s = 0.f;
    sh8 v = cvt8(in + (r0g + row) * 128 + sl * 8, s);
    *(sh8*)&a_t[(row * 16 + (sl ^ (row & 15))) * 8] = v;
    s += __shfl_xor(s, 1); s += __shfl_xor(s, 2);
    s += __shfl_xor(s, 4); s += __shfl_xor(s, 8);
    if ((lane & 15) == 0) km[r0g + row] = (s != 0.f) ? 1.f : 0.f;
  }
#pragma unroll
  for (int t = 0; t < 8; ++t) {
    const int u = t * 256 + tid, row = u >> 4, sl = u & 15;
    const float* src = (row < 64) ? (Wk + (size_t)row * 128) : (Wv + (size_t)(row - 64) * 128);
    float s = 0.f;
    sh8 v = cvt8(src + sl * 8, s);
    *(sh8*)&w_t[(row * 16 + (sl ^ (row & 15))) * 8] = v;
  }
  __syncthreads();

  const int r0 = wave * 32;
  sh8 a[2][4];
#pragma unroll
  for (int ri = 0; ri < 2; ++ri)
#pragma unroll
    for (int t = 0; t < 4; ++t) {
      const int row = r0 + ri * 16 + col;
      a[ri][t] = *(const sh8*)&a_t[(row * 16 + ((grp + 4 * t) ^ (row & 15))) * 8];
    }
  f4 acck[2][4], accv[2][8];
#pragma unroll
  for (int ri = 0; ri < 2; ++ri) {
#pragma unroll
    for (int jt = 0; jt < 4; ++jt) acck[ri][jt] = (f4)0.f;
#pragma unroll
    for (int jt = 0; jt < 8; ++jt) accv[ri][jt] = (f4)0.f;
  }
#pragma unroll
  for (int jt = 0; jt < 8; ++jt) {
    const int j = jt * 16 + col;
    sh8 bw[4];
#pragma unroll
    for (int t = 0; t < 4; ++t)
      bw[t] = *(const sh8*)&w_t[(j * 16 + ((grp + 4 * t) ^ (j & 15))) * 8];
#pragma unroll
    for (int ri = 0; ri < 2; ++ri)
#pragma unroll
      for (int t = 0; t < 4; ++t) {
        f4& dst = (jt < 4) ? acck[ri][jt] : accv[ri][jt - 4];
        dst = __builtin_amdgcn_mfma_f32_16x16x32_bf16(a[ri][t], bw[t], dst, 0, 0, 0);
      }
  }
#pragma unroll
  for (int jt = 0; jt < 4; ++jt) {
    const float bj = bk_[jt * 16 + col];
#pragma unroll
    for (int ri = 0; ri < 2; ++ri)
#pragma unroll
      for (int r = 0; r < 4; ++r)
        kit[(r0g + r0 + ri * 16 + grp * 4 + r) * 64 + jt * 16 + col] = f2bf(acck[ri][jt][r] + bj);
  }
  __syncthreads();
#pragma unroll
  for (int t = 0; t < 4; ++t) {
    const int u = t * 256 + tid, row = u >> 4, sl = u & 15;
    float s = 0.f;
    sh8 v = cvt8(Wv + (size_t)(64 + row) * 128 + sl * 8, s);
    *(sh8*)&w_t[(row * 16 + (sl ^ (row & 15))) * 8] = v;
  }
  __syncthreads();
#pragma unroll
  for (int jt = 0; jt < 4; ++jt) {
    const int j = jt * 16 + col;
    sh8 bw[4];
#pragma unroll
    for (int t = 0; t < 4; ++t)
      bw[t] = *(const sh8*)&w_t[(j * 16 + ((grp + 4 * t) ^ (j & 15))) * 8];
#pragma unroll
    for (int ri = 0; ri < 2; ++ri)
#pragma unroll
      for (int t = 0; t < 4; ++t)
        accv[ri][4 + jt] = __builtin_amdgcn_mfma_f32_16x16x32_bf16(a[ri][t], bw[t], accv[ri][4 + jt], 0, 0, 0);
  }
  __syncthreads();
  short* vtile = (short*)ulds;
#pragma unroll
  for (int vjt = 0; vjt < 8; ++vjt) {
    const int j = vjt * 16 + col;
    const float bvj = bv_[j];
#pragma unroll
    for (int ri = 0; ri < 2; ++ri)
#pragma unroll
      for (int r = 0; r < 4; ++r)
        vtile[j * 136 + r0 + ri * 16 + grp * 4 + r] = f2bf(accv[ri][vjt][r] + bvj);
  }
  __syncthreads();
  const int j2 = tid >> 1, half = tid & 1;
  short* dst = vt + ((size_t)(bb * 128 + j2)) * S_N + s0 + half * 64;
#pragma unroll
  for (int i = 0; i < 8; ++i)
    *(sh8*)(dst + i * 8) = *(const sh8*)&vtile[j2 * 136 + half * 64 + i * 8];
}

// ---------- Phase 2: fused attention — 128-KEY CHUNKS, bf16 noise in LDS ----------
// Evidence: R19 (64B->256B bursts) won; R20 (P-in-regs) null => attn is
// DRAM-efficiency-bound on the noise stream. This round: 512B noise bursts.
// Grid 512 (XCD-swizzled), 4 waves, 64 q-rows, 8 chunks of 128 keys.
// LDS: KV 64KB single-buffered (L2-hot; restaged after barrier) + noise
// 2 x 32KB BF16 double-buffered (reg-staged: coalesced dwordx4 -> cvt ->
// ds_write; HBM reads stay fp32; bf16 noise logit error ~2e-9, negligible)
// + kml 4KB = 132.5KB -> 1 block/CU (VGPR budget 512; ~190 live, no spill).
// Both pipeline waits are vmcnt(0) (no FIFO counting):
//   top:  vmcnt(0) = KV(k) landed -> barrier (noise(k) written in k-1)
//   post-PV: vmcnt(0) = noise-regs(k+1) -> cvt+ds_write -> lgkm -> barrier
//   -> stage KV(k+1) (overwrite safe: barrier proved all KV(k) reads done)
__global__ __launch_bounds__(256) void attn_kernel(
    const short* __restrict__ qit, const short* __restrict__ kit,
    const short* __restrict__ qctx, const short* __restrict__ kctx,
    const short* __restrict__ vt,     // [B,128,S] bf16
    const float* __restrict__ noise,  // [B,2,S,S]
    const float* __restrict__ sigma,  // [B,2]
    const float* __restrict__ qmask, const float* __restrict__ kmask,  // [B,S]
    const float* __restrict__ qin,    // queries_it [B,S,128]
    const float* __restrict__ W1, const float* __restrict__ b1,
    const float* __restrict__ W2, const float* __restrict__ b2,
    float* __restrict__ out) {
  // [0,64K): KV buf (K 16K | kctx 16K | V 32K) | [64K,128K): noise bf16 2x32K
  // | kml 4K | lsum
  __shared__ __align__(16) char lds_all[65536 + 2 * 32768 + 4096 + 512];
  float* kml = (float*)(lds_all + 131072);
  float* lsum = (float*)(lds_all + 131072 + 4096);  // [4][2][16]

  const int tid = threadIdx.x;
  const int wave = tid >> 6, lane = tid & 63;
  const int bid = blockIdx.x;
  const int wg = ((bid & 7) << 6) | (bid >> 3);  // XCD swizzle (512 % 8 == 0)
  const int b = wg >> 4, qt = wg & 15;
  const int qblk = qt * 64;
  const int qbase = qblk + wave * 16;
  const int col = lane & 15, grp = lane >> 4;
  const int swk = col & 7;

  const float w100 = W1[0], w101 = W1[1], w110 = W1[2], w111 = W1[3];
  const float bb10 = b1[0], bb11 = b1[1];
  const float sc = 0.125f;
  const float w200 = W2[0] * sc, w201 = W2[1] * sc, w210 = W2[2] * sc, w211 = W2[3] * sc;
  const float bb20 = b2[0] * sc, bb21 = b2[1] * sc;
  float sg0 = sigma[b * 2 + 0]; sg0 *= sg0;
  float sg1 = sigma[b * 2 + 1]; sg1 *= sg1;

  // Q fragments (B-operand of swapped QK^T): q = col, d = grp*8 + t*32
  const int qrow = qbase + col;
  sh8 aqit[2], aqctx[2];
#pragma unroll
  for (int t = 0; t < 2; ++t) {
    aqit[t] = *(const sh8*)(qit + ((size_t)(b * S_N + qrow)) * 64 + grp * 8 + t * 32);
    aqctx[t] = *(const sh8*)(qctx + ((size_t)(b * S_N + qrow)) * 64 + grp * 8 + t * 32);
  }

  f4 acc[2][4];
#pragma unroll
  for (int h = 0; h < 2; ++h)
#pragma unroll
    for (int dt = 0; dt < 4; ++dt) acc[h][dt] = (f4)0.f;
  float rs0 = 0.f, rs1 = 0.f;

  const float* nz_g = noise + (size_t)(b * 2) * S_N * S_N;
  const short* kit_g = kit + (size_t)b * S_N * 64;
  const short* kctx_g = kctx + (size_t)b * S_N * 64;
  const short* vt_g = vt + (size_t)b * 128 * S_N;

  for (int i = tid; i < 1024; i += 256) kml[i] = kmask[(size_t)b * S_N + i];

  // KV stage for a 128-key chunk: 16 x 1KB global_load_lds per wave.
  // wave0=K(16K), wave1=kctx(16K), waves2,3=V(32K). Src pre-swizzled.
  auto STAGE_KV = [&](int kc) {
    char* buf = lds_all;
    if (wave == 0) {
#pragma unroll
      for (int i = 0; i < 16; ++i) {  // K: [128 rows][8 sl of 8sh], swz sl^(row&7)
        const int g = i * 64 + lane, row = g >> 3, sl = g & 7;
        const short* p = kit_g + (size_t)(kc + row) * 64 + ((sl ^ (row & 7)) << 3);
        __builtin_amdgcn_global_load_lds((const AS1 unsigned*)p,
                                         (AS3 unsigned*)(buf + i * 1024), 16, 0, 0);
      }
    } else if (wave == 1) {
#pragma unroll
      for (int i = 0; i < 16; ++i) {  // kctx
        const int g = i * 64 + lane, row = g >> 3, sl = g & 7;
        const short* p = kctx_g + (size_t)(kc + row) * 64 + ((sl ^ (row & 7)) << 3);
        __builtin_amdgcn_global_load_lds((const AS1 unsigned*)p,
                                         (AS3 unsigned*)(buf + 16384 + i * 1024), 16, 0, 0);
      }
    } else {
#pragma unroll
      for (int i = 0; i < 16; ++i) {  // V: [128 d][16 sl of 8sh], swz sl^(d&15)
        const int vi = (wave - 2) * 16 + i;
        const int g = vi * 64 + lane, d = g >> 4, sl = g & 15;
        const short* p = vt_g + (size_t)d * S_N + kc + ((sl ^ (d & 15)) << 3);
        __builtin_amdgcn_global_load_lds((const AS1 unsigned*)p,
                                         (AS3 unsigned*)(buf + 32768 + vi * 1024), 16, 0, 0);
      }
    }
  };

  // Noise reg loads for a chunk: 16 coalesced dwordx4/lane covering the wave's
  // PRIVATE [2 head][16 q][128 k] f32 slice; per (head,q) row = 512B contig.
  f4 nr[16];
  auto NOISE_LOAD = [&](int kc) {
#pragma unroll
    for (int i = 0; i < 16; ++i) {
      const int g = i * 64 + lane;
      const int head = g >> 9, q = (g >> 5) & 15, jf4 = g & 31;
      nr[i] = *(const f4*)(nz_g + (size_t)head * S_N * S_N +
                           (size_t)(qbase + q) * S_N + kc + jf4 * 4);
    }
  };
  // Convert + write to bf16 noise buf (LDS-domain XOR j^q on 16B slots).
  auto NOISE_WRITE = [&](int parity) {
    short* nb = (short*)(lds_all + 65536 + parity * 32768 + wave * 8192);
#pragma unroll
    for (int i = 0; i < 16; ++i) {
      const int g = i * 64 + lane;
      const int head = g >> 9, q = (g >> 5) & 15, jf4 = g & 31;
      const int j = jf4 >> 1, half = jf4 & 1;
      sh4 w;
#pragma unroll
      for (int e = 0; e < 4; ++e) w[e] = f2bf(nr[i][e]);
      *(sh4*)&nb[head * 2048 + q * 128 + ((j ^ q) << 3) + half * 4] = w;
    }
  };

  // prologue: chunk 0
  STAGE_KV(0);
  NOISE_LOAD(0);
  asm volatile("s_waitcnt vmcnt(0)" ::: "memory");
  __builtin_amdgcn_sched_barrier(0);
  NOISE_WRITE(0);
  asm volatile("s_waitcnt lgkmcnt(0)" ::: "memory");
  __builtin_amdgcn_s_barrier();

#pragma unroll 1
  for (int k = 0; k < 8; ++k) {
    const int kc = k * 128;
    // (top barrier of iter k is the epilogue barrier of k-1 / prologue)
    if (k + 1 < 8) NOISE_LOAD(kc + 128);  // HBM, in flight across compute

    const short* Kb = (const short*)lds_all;
    const short* Cb = (const short*)(lds_all + 16384);
    const short* Vb = (const short*)(lds_all + 32768);
    const short* Nw = (const short*)(lds_all + 65536 + (k & 1) * 32768 + wave * 8192);

    // --- QK^T (swapped): per kt, C = S^T: key = kt*16 + grp*4 + r, q = col
    f4 sit[8], sctx[8];
#pragma unroll
    for (int kt = 0; kt < 8; ++kt) {
      const int krow = kt * 16 + col;
      sit[kt] = (f4)0.f;
      sctx[kt] = (f4)0.f;
#pragma unroll
      for (int t = 0; t < 2; ++t) {
        const int so = ((grp + 4 * t) ^ swk) * 8;
        sh8 bk = *(const sh8*)&Kb[krow * 64 + so];
        sit[kt] = __builtin_amdgcn_mfma_f32_16x16x32_bf16(bk, aqit[t], sit[kt], 0, 0, 0);
        sh8 bc = *(const sh8*)&Cb[krow * 64 + so];
        sctx[kt] = __builtin_amdgcn_mfma_f32_16x16x32_bf16(bc, aqctx[t], sctx[kt], 0, 0, 0);
      }
    }
    // --- per kt: MLP + exp + mask -> P regs -> PV (16x16x16)
#pragma unroll
    for (int kt = 0; kt < 8; ++kt) {
      const int j = kt * 2 + (grp >> 1);
      const int noff = ((j ^ col) << 3) + (grp & 1) * 4;
      sh4 n0v = *(const sh4*)&Nw[col * 128 + noff];
      sh4 n1v = *(const sh4*)&Nw[2048 + col * 128 + noff];
      f4 km = *(const f4*)&kml[kc + kt * 16 + grp * 4];
      sh4 po, pc;
#pragma unroll
      for (int r = 0; r < 4; ++r) {
        float x0 = fmaf(bf2f(n0v[r]), sg0, sit[kt][r]);
        float x1 = fmaf(bf2f(n1v[r]), sg1, sctx[kt][r]);
        float h0 = fmaxf(fmaf(w101, x1, fmaf(w100, x0, bb10)), 0.f);
        float h1 = fmaxf(fmaf(w111, x1, fmaf(w110, x0, bb11)), 0.f);
        float L0 = fmaf(w201, h1, fmaf(w200, h0, bb20));
        float L1 = fmaf(w211, h1, fmaf(w210, h0, bb21));
        float p0 = __expf(L0) * km[r];
        float p1 = __expf(L1) * km[r];
        rs0 += p0;
        rs1 += p1;
        po[r] = f2bf(p0);
        pc[r] = f2bf(p1);
      }
#pragma unroll
      for (int h = 0; h < 2; ++h) {
        const sh4 pa = h ? pc : po;
#pragma unroll
        for (int dt = 0; dt < 4; ++dt) {
          const int drow = h * 64 + dt * 16 + col;
          sh4 bv = *(const sh4*)&Vb[drow * 128 + ((j ^ (drow & 15)) << 3) + (grp & 1) * 4];
          acc[h][dt] = mfma16(pa, bv, acc[h][dt]);
        }
      }
    }
    // --- epilogue of chunk k: land + write next noise, then restage KV
    if (k + 1 < 8) {
      asm volatile("s_waitcnt vmcnt(0)" ::: "memory");  // noise regs (k+1)
      __builtin_amdgcn_sched_barrier(0);
      NOISE_WRITE((k + 1) & 1);
    }
    asm volatile("s_waitcnt lgkmcnt(0)" ::: "memory");
    __builtin_amdgcn_s_barrier();  // KV(k) reads done block-wide; noise(k+1) visible
    if (k + 1 < 8) STAGE_KV(kc + 128);  // overwrite KV buf (safe post-barrier)
  }

  // sum-exp: reduce over the 4 lanes sharing q=col, redistribute via LDS
  rs0 += __shfl_xor(rs0, 16); rs0 += __shfl_xor(rs0, 32);
  rs1 += __shfl_xor(rs1, 16); rs1 += __shfl_xor(rs1, 32);
  if (lane < 16) {
    lsum[(wave * 2 + 0) * 16 + col] = rs0;
    lsum[(wave * 2 + 1) * 16 + col] = rs1;
  }
  __syncthreads();
  f4 ls0 = *(const f4*)&lsum[(wave * 2 + 0) * 16 + grp * 4];
  f4 ls1 = *(const f4*)&lsum[(wave * 2 + 1) * 16 + grp * 4];
  f4 qm4 = *(const f4*)(qmask + (size_t)b * S_N + qbase + grp * 4);
#pragma unroll
  for (int h = 0; h < 2; ++h)
#pragma unroll
    for (int dt = 0; dt < 4; ++dt)
#pragma unroll
      for (int r = 0; r < 4; ++r) {
        const float s2 = qm4[r] / (h ? ls1[r] : ls0[r]);
        const size_t o = ((size_t)(b * S_N + qbase + grp * 4 + r)) * 128 + h * 64 + dt * 16 + col;
        out[o] = acc[h][dt][r] * s2 + qin[o];
      }
}

extern "C" void kernel_launch(void* const* d_in, const int* in_sizes, int n_in,
                              void* d_out, int out_size, void* d_ws, size_t ws_size,
                              hipStream_t stream) {
  const float* queries_it = (const float*)d_in[0];
  const float* queries_ctx = (const float*)d_in[1];
  const float* keys_it = (const float*)d_in[2];
  const float* keys_ctx = (const float*)d_in[3];
  const float* sigma = (const float*)d_in[4];
  const float* noise = (const float*)d_in[5];
  const float* Wq_it = (const float*)d_in[6];
  const float* bq_it = (const float*)d_in[7];
  const float* Wk_it = (const float*)d_in[8];
  const float* bk_it = (const float*)d_in[9];
  const float* Wq_ctx = (const float*)d_in[10];
  const float* bq_ctx = (const float*)d_in[11];
  const float* Wk_ctx = (const float*)d_in[12];
  const float* bk_ctx = (const float*)d_in[13];
  const float* Wv = (const float*)d_in[14];
  const float* bv = (const float*)d_in[15];
  const float* W1 = (const float*)d_in[16];
  const float* b1 = (const float*)d_in[17];
  const float* W2 = (const float*)d_in[18];
  const float* b2 = (const float*)d_in[19];
  float* out = (float*)d_out;

  char* ws = (char*)d_ws;
  short* qit = (short*)(ws);                    // 4 MB
  short* kit = (short*)(ws + (4ull << 20));     // 4 MB
  short* qctx = (short*)(ws + (8ull << 20));    // 4 MB
  short* kctx = (short*)(ws + (12ull << 20));   // 4 MB
  short* vt = (short*)(ws + (16ull << 20));     // 8 MB  [B,128,S]
  float* qmask = (float*)(ws + (24ull << 20));  // 128 KB
  float* kmask = (float*)(ws + (24ull << 20) + (size_t)B_N * S_N * 4);

  const int NB = B_N * S_N / 128;  // 256 blocks per projection
  proj_q_kernel<<<dim3(NB), 256, 0, stream>>>(queries_it, Wq_it, bq_it, qit, qmask);
  proj_k_mfma<<<dim3(NB), 256, 0, stream>>>(keys_it, Wk_it, bk_it, Wv, bv, kit, vt, kmask);
  proj_ctx2_kernel<<<dim3(2 * NB), 256, 0, stream>>>(
      queries_ctx, Wq_ctx, bq_ctx, qctx, keys_ctx, Wk_ctx, bk_ctx, kctx, NB);

  attn_kernel<<<dim3(B_N * (S_N / 64)), 256, 0, stream>>>(
      qit, kit, qctx, kctx, vt, noise, sigma, qmask, kmask, queries_it,
      W1, b1, W2, b2, out);
}

// Round 22
// 112.140 us; speedup vs baseline: 1.3177x; 1.3177x over previous
//
#include <hip/hip_runtime.h>

#define B_N 32
#define S_N 1024

typedef __attribute__((ext_vector_type(8))) short sh8;
typedef __attribute__((ext_vector_type(4))) short sh4;
typedef __attribute__((ext_vector_type(4))) float f4;

#define AS1 __attribute__((address_space(1)))
#define AS3 __attribute__((address_space(3)))

__device__ __forceinline__ short f2bf(float f) {
  unsigned u = __builtin_bit_cast(unsigned, f);
  u += 0x7fff + ((u >> 16) & 1);
  return (short)(u >> 16);
}

#if defined(__has_builtin)
#if __has_builtin(__builtin_amdgcn_mfma_f32_16x16x16bf16_1k)
#define HAVE_MFMA16 1
#endif
#endif
__device__ __forceinline__ f4 mfma16(sh4 a, sh4 b, f4 c) {
#ifdef HAVE_MFMA16
  return __builtin_amdgcn_mfma_f32_16x16x16bf16_1k(a, b, c, 0, 0, 0);
#else
  asm volatile("v_mfma_f32_16x16x16_bf16 %0, %1, %2, %0\n\ts_nop 7\n\ts_nop 7"
               : "+v"(c) : "v"(a), "v"(b));
  return c;
#endif
}

// convert 8 consecutive f32 at src to sh8, also return abs-sum
__device__ __forceinline__ sh8 cvt8(const float* src, float& s) {
  f4 x0 = *(const f4*)src;
  f4 x1 = *(const f4*)(src + 4);
  sh8 v;
#pragma unroll
  for (int i = 0; i < 4; ++i) {
    v[i] = f2bf(x0[i]);
    v[4 + i] = f2bf(x1[i]);
    s += fabsf(x0[i]) + fabsf(x1[i]);
  }
  return v;
}

// ---------- Phase 1 (MFMA): generic 128-row x 64-col projection body ----------
template <int DIN, bool MASK>
__device__ __forceinline__ void dev_proj(
    const float* __restrict__ in, const float* __restrict__ W,
    const float* __restrict__ bias, short* __restrict__ out,
    float* __restrict__ mask, int blk) {
  constexpr int NSL = DIN / 8;
  constexpr int KT = DIN / 32;
  __shared__ __align__(16) short a_t[128 * DIN];
  __shared__ __align__(16) short w_t[64 * DIN];
  const int tid = threadIdx.x;
  const int wave = tid >> 6, lane = tid & 63;
  const int col = lane & 15, grp = lane >> 4;
  const size_t r0g = (size_t)blk * 128;

#pragma unroll
  for (int t = 0; t < 128 * NSL / 256; ++t) {
    const int u = t * 256 + tid, row = u / NSL, sl = u % NSL;
    float s = 0.f;
    sh8 v = cvt8(in + (r0g + row) * DIN + sl * 8, s);
    *(sh8*)&a_t[(row * NSL + (sl ^ (row & (NSL - 1)))) * 8] = v;
    if (MASK) {
      s += __shfl_xor(s, 1); s += __shfl_xor(s, 2);
      s += __shfl_xor(s, 4); s += __shfl_xor(s, 8);
      if ((lane & 15) == 0) mask[r0g + row] = (s != 0.f) ? 1.f : 0.f;
    }
  }
#pragma unroll
  for (int t = 0; t < 64 * NSL / 256; ++t) {
    const int u = t * 256 + tid, row = u / NSL, sl = u % NSL;
    float s = 0.f;
    sh8 v = cvt8(W + (size_t)row * DIN + sl * 8, s);
    *(sh8*)&w_t[(row * NSL + (sl ^ (row & (NSL - 1)))) * 8] = v;
  }
  __syncthreads();

  const int r0 = wave * 32;
  sh8 a[2][KT];
#pragma unroll
  for (int ri = 0; ri < 2; ++ri)
#pragma unroll
    for (int t = 0; t < KT; ++t) {
      const int row = r0 + ri * 16 + col;
      a[ri][t] = *(const sh8*)&a_t[(row * NSL + ((grp + 4 * t) ^ (row & (NSL - 1)))) * 8];
    }
  f4 acc[2][4];
#pragma unroll
  for (int ri = 0; ri < 2; ++ri)
#pragma unroll
    for (int jt = 0; jt < 4; ++jt) acc[ri][jt] = (f4)0.f;
#pragma unroll
  for (int jt = 0; jt < 4; ++jt) {
    const int j = jt * 16 + col;
    sh8 bw[KT];
#pragma unroll
    for (int t = 0; t < KT; ++t)
      bw[t] = *(const sh8*)&w_t[(j * NSL + ((grp + 4 * t) ^ (j & (NSL - 1)))) * 8];
#pragma unroll
    for (int ri = 0; ri < 2; ++ri)
#pragma unroll
      for (int t = 0; t < KT; ++t)
        acc[ri][jt] = __builtin_amdgcn_mfma_f32_16x16x32_bf16(a[ri][t], bw[t], acc[ri][jt], 0, 0, 0);
  }
#pragma unroll
  for (int jt = 0; jt < 4; ++jt) {
    const float bj = bias[jt * 16 + col];
#pragma unroll
    for (int ri = 0; ri < 2; ++ri)
#pragma unroll
      for (int r = 0; r < 4; ++r)
        out[(r0g + r0 + ri * 16 + grp * 4 + r) * 64 + jt * 16 + col] = f2bf(acc[ri][jt][r] + bj);
  }
}

__global__ __launch_bounds__(256) void proj_q_kernel(
    const float* __restrict__ in, const float* __restrict__ W,
    const float* __restrict__ bias, short* __restrict__ out,
    float* __restrict__ mask) {
  dev_proj<128, true>(in, W, bias, out, mask, blockIdx.x);
}

__global__ __launch_bounds__(256) void proj_ctx2_kernel(
    const float* __restrict__ in0, const float* __restrict__ W0,
    const float* __restrict__ b0, short* __restrict__ o0,
    const float* __restrict__ in1, const float* __restrict__ W1_,
    const float* __restrict__ b1_, short* __restrict__ o1, int nb) {
  const int sel = blockIdx.x >= nb;
  const int blk = sel ? (blockIdx.x - nb) : blockIdx.x;
  dev_proj<64, false>(sel ? in1 : in0, sel ? W1_ : W0, sel ? b1_ : b0,
                      sel ? o1 : o0, nullptr, blk);
}

// ---------- Phase 1 (MFMA): K projection + V (128 cols, transposed) + kmask ----------
__global__ __launch_bounds__(256) void proj_k_mfma(
    const float* __restrict__ in, const float* __restrict__ Wk, const float* __restrict__ bk_,
    const float* __restrict__ Wv, const float* __restrict__ bv_,
    short* __restrict__ kit, short* __restrict__ vt, float* __restrict__ km) {
  __shared__ __align__(16) char ulds[65536];
  short* a_t = (short*)ulds;
  short* w_t = (short*)(ulds + 32768);
  const int tid = threadIdx.x;
  const int wave = tid >> 6, lane = tid & 63;
  const int col = lane & 15, grp = lane >> 4;
  const size_t r0g = (size_t)blockIdx.x * 128;
  const int bb = (int)(r0g >> 10), s0 = (int)(r0g & 1023);

#pragma unroll
  for (int t = 0; t < 8; ++t) {
    const int u = t * 256 + tid, row = u >> 4, sl = u & 15;
    float s = 0.f;
    sh8 v = cvt8(in + (r0g + row) * 128 + sl * 8, s);
    *(sh8*)&a_t[(row * 16 + (sl ^ (row & 15))) * 8] = v;
    s += __shfl_xor(s, 1); s += __shfl_xor(s, 2);
    s += __shfl_xor(s, 4); s += __shfl_xor(s, 8);
    if ((lane & 15) == 0) km[r0g + row] = (s != 0.f) ? 1.f : 0.f;
  }
#pragma unroll
  for (int t = 0; t < 8; ++t) {
    const int u = t * 256 + tid, row = u >> 4, sl = u & 15;
    const float* src = (row < 64) ? (Wk + (size_t)row * 128) : (Wv + (size_t)(row - 64) * 128);
    float s = 0.f;
    sh8 v = cvt8(src + sl * 8, s);
    *(sh8*)&w_t[(row * 16 + (sl ^ (row & 15))) * 8] = v;
  }
  __syncthreads();

  const int r0 = wave * 32;
  sh8 a[2][4];
#pragma unroll
  for (int ri = 0; ri < 2; ++ri)
#pragma unroll
    for (int t = 0; t < 4; ++t) {
      const int row = r0 + ri * 16 + col;
      a[ri][t] = *(const sh8*)&a_t[(row * 16 + ((grp + 4 * t) ^ (row & 15))) * 8];
    }
  f4 acck[2][4], accv[2][8];
#pragma unroll
  for (int ri = 0; ri < 2; ++ri) {
#pragma unroll
    for (int jt = 0; jt < 4; ++jt) acck[ri][jt] = (f4)0.f;
#pragma unroll
    for (int jt = 0; jt < 8; ++jt) accv[ri][jt] = (f4)0.f;
  }
#pragma unroll
  for (int jt = 0; jt < 8; ++jt) {
    const int j = jt * 16 + col;
    sh8 bw[4];
#pragma unroll
    for (int t = 0; t < 4; ++t)
      bw[t] = *(const sh8*)&w_t[(j * 16 + ((grp + 4 * t) ^ (j & 15))) * 8];
#pragma unroll
    for (int ri = 0; ri < 2; ++ri)
#pragma unroll
      for (int t = 0; t < 4; ++t) {
        f4& dst = (jt < 4) ? acck[ri][jt] : accv[ri][jt - 4];
        dst = __builtin_amdgcn_mfma_f32_16x16x32_bf16(a[ri][t], bw[t], dst, 0, 0, 0);
      }
  }
#pragma unroll
  for (int jt = 0; jt < 4; ++jt) {
    const float bj = bk_[jt * 16 + col];
#pragma unroll
    for (int ri = 0; ri < 2; ++ri)
#pragma unroll
      for (int r = 0; r < 4; ++r)
        kit[(r0g + r0 + ri * 16 + grp * 4 + r) * 64 + jt * 16 + col] = f2bf(acck[ri][jt][r] + bj);
  }
  __syncthreads();
#pragma unroll
  for (int t = 0; t < 4; ++t) {
    const int u = t * 256 + tid, row = u >> 4, sl = u & 15;
    float s = 0.f;
    sh8 v = cvt8(Wv + (size_t)(64 + row) * 128 + sl * 8, s);
    *(sh8*)&w_t[(row * 16 + (sl ^ (row & 15))) * 8] = v;
  }
  __syncthreads();
#pragma unroll
  for (int jt = 0; jt < 4; ++jt) {
    const int j = jt * 16 + col;
    sh8 bw[4];
#pragma unroll
    for (int t = 0; t < 4; ++t)
      bw[t] = *(const sh8*)&w_t[(j * 16 + ((grp + 4 * t) ^ (j & 15))) * 8];
#pragma unroll
    for (int ri = 0; ri < 2; ++ri)
#pragma unroll
      for (int t = 0; t < 4; ++t)
        accv[ri][4 + jt] = __builtin_amdgcn_mfma_f32_16x16x32_bf16(a[ri][t], bw[t], accv[ri][4 + jt], 0, 0, 0);
  }
  __syncthreads();
  short* vtile = (short*)ulds;
#pragma unroll
  for (int vjt = 0; vjt < 8; ++vjt) {
    const int j = vjt * 16 + col;
    const float bvj = bv_[j];
#pragma unroll
    for (int ri = 0; ri < 2; ++ri)
#pragma unroll
      for (int r = 0; r < 4; ++r)
        vtile[j * 136 + r0 + ri * 16 + grp * 4 + r] = f2bf(accv[ri][vjt][r] + bvj);
  }
  __syncthreads();
  const int j2 = tid >> 1, half = tid & 1;
  short* dst = vt + ((size_t)(bb * 128 + j2)) * S_N + s0 + half * 64;
#pragma unroll
  for (int i = 0; i < 8; ++i)
    *(sh8*)(dst + i * 8) = *(const sh8*)&vtile[j2 * 136 + half * 64 + i * 8];
}

// ---------- Phase 2: fused attention — R20 base + NON-TEMPORAL noise loads ----------
// R20 (512 blocks XCD-swizzled, 4 waves, 64 q-rows, 16 chunks of 64 keys,
// 2 x 64KB bufs, split counted waits vmcnt(8)/vmcnt(16), P in registers).
// ONE change: noise global_load_lds uses aux=2 (gfx94x/gfx950 CPol NT bit) so
// the 268MB noise stream bypasses/evicts-less L2 -> the 512KB/batch K/kctx/V
// working set stays L2-resident and its 16x re-reads become L2 hits instead
// of falling through to L3 (theory: L3 BW on noise+KV-re-reads is the current
// binding resource; cache policy cannot affect correctness).
__global__ __launch_bounds__(256) void attn_kernel(
    const short* __restrict__ qit, const short* __restrict__ kit,
    const short* __restrict__ qctx, const short* __restrict__ kctx,
    const short* __restrict__ vt,     // [B,128,S] bf16
    const float* __restrict__ noise,  // [B,2,S,S]
    const float* __restrict__ sigma,  // [B,2]
    const float* __restrict__ qmask, const float* __restrict__ kmask,  // [B,S]
    const float* __restrict__ qin,    // queries_it [B,S,128]
    const float* __restrict__ W1, const float* __restrict__ b1,
    const float* __restrict__ W2, const float* __restrict__ b2,
    float* __restrict__ out) {
  // [0,128K): two 64KB chunk bufs | kml 4K | lsum
  __shared__ __align__(16) char lds_all[2 * 65536 + 4096 + 512];
  float* kml = (float*)(lds_all + 2 * 65536);
  float* lsum = (float*)(lds_all + 2 * 65536 + 4096);  // [4][2][16]

  const int tid = threadIdx.x;
  const int wave = tid >> 6, lane = tid & 63;
  const int bid = blockIdx.x;
  const int wg = ((bid & 7) << 6) | (bid >> 3);  // XCD swizzle (512 % 8 == 0)
  const int b = wg >> 4, qt = wg & 15;
  const int qblk = qt * 64;
  const int qbase = qblk + wave * 16;
  const int col = lane & 15, grp = lane >> 4;
  const int swk = col & 7;

  const float w100 = W1[0], w101 = W1[1], w110 = W1[2], w111 = W1[3];
  const float bb10 = b1[0], bb11 = b1[1];
  const float sc = 0.125f;
  const float w200 = W2[0] * sc, w201 = W2[1] * sc, w210 = W2[2] * sc, w211 = W2[3] * sc;
  const float bb20 = b2[0] * sc, bb21 = b2[1] * sc;
  float sg0 = sigma[b * 2 + 0]; sg0 *= sg0;
  float sg1 = sigma[b * 2 + 1]; sg1 *= sg1;

  // Q fragments (B-operand of swapped QK^T): q = col, d = grp*8 + t*32
  const int qrow = qbase + col;
  sh8 aqit[2], aqctx[2];
#pragma unroll
  for (int t = 0; t < 2; ++t) {
    aqit[t] = *(const sh8*)(qit + ((size_t)(b * S_N + qrow)) * 64 + grp * 8 + t * 32);
    aqctx[t] = *(const sh8*)(qctx + ((size_t)(b * S_N + qrow)) * 64 + grp * 8 + t * 32);
  }

  f4 acc[2][4];
#pragma unroll
  for (int h = 0; h < 2; ++h)
#pragma unroll
    for (int dt = 0; dt < 4; ++dt) acc[h][dt] = (f4)0.f;
  float rs0 = 0.f, rs1 = 0.f;

  const float* nz_g = noise + (size_t)(b * 2) * S_N * S_N;
  const short* kit_g = kit + (size_t)b * S_N * 64;
  const short* kctx_g = kctx + (size_t)b * S_N * 64;
  const short* vt_g = vt + (size_t)b * 128 * S_N;

  for (int i = tid; i < 1024; i += 256) kml[i] = kmask[(size_t)b * S_N + i];
  __syncthreads();  // kml visible (also drains its vmcnt before pipeline starts)

  // KV stage: 8 loads/wave. wave0=K(8K), wave1=kctx(8K), wave2+3=V(16K).
  auto STAGE_KV = [&](char* buf, int kc) {
    if (wave == 0) {
#pragma unroll
      for (int i = 0; i < 8; ++i) {  // K: [64 rows][8 sl], src-swz sl^(row&7)
        const int idx = i * 64 + lane, row = idx >> 3, sl = idx & 7;
        const short* g = kit_g + (size_t)(kc + row) * 64 + ((sl ^ (row & 7)) << 3);
        __builtin_amdgcn_global_load_lds((const AS1 unsigned*)g,
                                         (AS3 unsigned*)(buf + i * 1024), 16, 0, 0);
      }
    } else if (wave == 1) {
#pragma unroll
      for (int i = 0; i < 8; ++i) {  // kctx
        const int idx = i * 64 + lane, row = idx >> 3, sl = idx & 7;
        const short* g = kctx_g + (size_t)(kc + row) * 64 + ((sl ^ (row & 7)) << 3);
        __builtin_amdgcn_global_load_lds((const AS1 unsigned*)g,
                                         (AS3 unsigned*)(buf + 8192 + i * 1024), 16, 0, 0);
      }
    } else {
#pragma unroll
      for (int i = 0; i < 8; ++i) {  // V: [128 d][8 sl], src-swz sl^(d&7)
        const int vi = (wave - 2) * 8 + i;
        const int idx = vi * 64 + lane, d = idx >> 3, sl = idx & 7;
        const short* g = vt_g + (size_t)d * S_N + kc + ((sl ^ (d & 7)) << 3);
        __builtin_amdgcn_global_load_lds((const AS1 unsigned*)g,
                                         (AS3 unsigned*)(buf + 16384 + vi * 1024), 16, 0, 0);
      }
    }
  };
  // Noise stage: 8 loads/wave, PRIVATE [2 head][16 q][16 granules], phi = j^q.
  // Per q-row the 16 granules cover 256 B CONTIGUOUS global memory.
  // aux=2 -> NT (non-temporal): stream past L2, keep KV resident.
  auto STAGE_N = [&](char* buf, int kc) {
#pragma unroll
    for (int i = 0; i < 8; ++i) {
      const int idx = i * 64 + lane;
      const int head = idx >> 8, q = (idx >> 4) & 15, phi = idx & 15;
      const int j = phi ^ q;
      const float* g = nz_g + (size_t)head * S_N * S_N + (size_t)(qbase + q) * S_N + kc + j * 4;
      __builtin_amdgcn_global_load_lds((const AS1 unsigned*)g,
                                       (AS3 unsigned*)(buf + 32768 + wave * 8192 + i * 1024), 16, 0, 2);
    }
  };

  STAGE_KV(lds_all, 0);
  STAGE_N(lds_all, 0);

#pragma unroll 1
  for (int k = 0; k < 16; ++k) {
    char* cur = lds_all + (size_t)(k & 1) * 65536;
    char* nxt = lds_all + (size_t)((k + 1) & 1) * 65536;
    const int kc = k * 64;
    // own KV(k) done: younger = N(k) = 8
    asm volatile("s_waitcnt vmcnt(8)" ::: "memory");
    __builtin_amdgcn_sched_barrier(0);
    // block-wide: everyone's KV(k) landed; chunk k-1 fully consumed -> nxt free
    __builtin_amdgcn_s_barrier();
    {
      const int kc2 = ((k + 1) & 15) * 64;
      STAGE_KV(nxt, kc2);
      STAGE_N(nxt, kc2);
    }

    const short* Kb = (const short*)cur;
    const short* Cb = (const short*)(cur + 8192);
    const short* Vb = (const short*)(cur + 16384);
    const float* Nw = (const float*)(cur + 32768 + wave * 8192);

    // --- QK^T (swapped): per kt, C = S^T: key = kt*16 + grp*4 + r, q = col
    f4 sit[4], sctx[4];
#pragma unroll
    for (int kt = 0; kt < 4; ++kt) {
      const int krow = kt * 16 + col;
      sit[kt] = (f4)0.f;
      sctx[kt] = (f4)0.f;
#pragma unroll
      for (int t = 0; t < 2; ++t) {
        const int so = ((grp + 4 * t) ^ swk) * 8;
        sh8 bk = *(const sh8*)&Kb[krow * 64 + so];
        sit[kt] = __builtin_amdgcn_mfma_f32_16x16x32_bf16(bk, aqit[t], sit[kt], 0, 0, 0);
        sh8 bc = *(const sh8*)&Cb[krow * 64 + so];
        sctx[kt] = __builtin_amdgcn_mfma_f32_16x16x32_bf16(bc, aqctx[t], sctx[kt], 0, 0, 0);
      }
    }
    // own N(k) done: younger = KV(k+1)+N(k+1) = 16 (per-wave stall only)
    asm volatile("s_waitcnt vmcnt(16)" ::: "memory");
    __builtin_amdgcn_sched_barrier(0);

    // --- per kt: MLP + exp + mask -> P in registers -> PV (16x16x16 MFMA)
#pragma unroll
    for (int kt = 0; kt < 4; ++kt) {
      const int phi = (kt * 4 + grp) ^ col;
      f4 n0 = *(const f4*)&Nw[col * 64 + phi * 4];
      f4 n1 = *(const f4*)&Nw[1024 + col * 64 + phi * 4];
      f4 km = *(const f4*)&kml[kc + kt * 16 + grp * 4];
      sh4 po, pc;
#pragma unroll
      for (int r = 0; r < 4; ++r) {
        float x0 = fmaf(n0[r], sg0, sit[kt][r]);
        float x1 = fmaf(n1[r], sg1, sctx[kt][r]);
        float h0 = fmaxf(fmaf(w101, x1, fmaf(w100, x0, bb10)), 0.f);
        float h1 = fmaxf(fmaf(w111, x1, fmaf(w110, x0, bb11)), 0.f);
        float L0 = fmaf(w201, h1, fmaf(w200, h0, bb20));
        float L1 = fmaf(w211, h1, fmaf(w210, h0, bb21));
        float p0 = __expf(L0) * km[r];
        float p1 = __expf(L1) * km[r];
        rs0 += p0;
        rs1 += p1;
        po[r] = f2bf(p0);
        pc[r] = f2bf(p1);
      }
      // PV: A = po/pc (A-frag: q=col, key=grp*4+r), B = V[drow][kt*16+grp*4..+4]
      const int j = kt * 2 + (grp >> 1);
#pragma unroll
      for (int h = 0; h < 2; ++h) {
        const sh4 pa = h ? pc : po;
#pragma unroll
        for (int dt = 0; dt < 4; ++dt) {
          const int drow = h * 64 + dt * 16 + col;
          sh4 bv = *(const sh4*)&Vb[drow * 64 + ((j ^ (drow & 7)) << 3) + (grp & 1) * 4];
          acc[h][dt] = mfma16(pa, bv, acc[h][dt]);
        }
      }
    }
  }

  // sum-exp: reduce over the 4 lanes sharing q=col, redistribute via LDS
  rs0 += __shfl_xor(rs0, 16); rs0 += __shfl_xor(rs0, 32);
  rs1 += __shfl_xor(rs1, 16); rs1 += __shfl_xor(rs1, 32);
  if (lane < 16) {
    lsum[(wave * 2 + 0) * 16 + col] = rs0;
    lsum[(wave * 2 + 1) * 16 + col] = rs1;
  }
  __syncthreads();
  f4 ls0 = *(const f4*)&lsum[(wave * 2 + 0) * 16 + grp * 4];
  f4 ls1 = *(const f4*)&lsum[(wave * 2 + 1) * 16 + grp * 4];
  f4 qm4 = *(const f4*)(qmask + (size_t)b * S_N + qbase + grp * 4);
#pragma unroll
  for (int h = 0; h < 2; ++h)
#pragma unroll
    for (int dt = 0; dt < 4; ++dt)
#pragma unroll
      for (int r = 0; r < 4; ++r) {
        const float s2 = qm4[r] / (h ? ls1[r] : ls0[r]);
        const size_t o = ((size_t)(b * S_N + qbase + grp * 4 + r)) * 128 + h * 64 + dt * 16 + col;
        out[o] = acc[h][dt][r] * s2 + qin[o];
      }
}

extern "C" void kernel_launch(void* const* d_in, const int* in_sizes, int n_in,
                              void* d_out, int out_size, void* d_ws, size_t ws_size,
                              hipStream_t stream) {
  const float* queries_it = (const float*)d_in[0];
  const float* queries_ctx = (const float*)d_in[1];
  const float* keys_it = (const float*)d_in[2];
  const float* keys_ctx = (const float*)d_in[3];
  const float* sigma = (const float*)d_in[4];
  const float* noise = (const float*)d_in[5];
  const float* Wq_it = (const float*)d_in[6];
  const float* bq_it = (const float*)d_in[7];
  const float* Wk_it = (const float*)d_in[8];
  const float* bk_it = (const float*)d_in[9];
  const float* Wq_ctx = (const float*)d_in[10];
  const float* bq_ctx = (const float*)d_in[11];
  const float* Wk_ctx = (const float*)d_in[12];
  const float* bk_ctx = (const float*)d_in[13];
  const float* Wv = (const float*)d_in[14];
  const float* bv = (const float*)d_in[15];
  const float* W1 = (const float*)d_in[16];
  const float* b1 = (const float*)d_in[17];
  const float* W2 = (const float*)d_in[18];
  const float* b2 = (const float*)d_in[19];
  float* out = (float*)d_out;

  char* ws = (char*)d_ws;
  short* qit = (short*)(ws);                    // 4 MB
  short* kit = (short*)(ws + (4ull << 20));     // 4 MB
  short* qctx = (short*)(ws + (8ull << 20));    // 4 MB
  short* kctx = (short*)(ws + (12ull << 20));   // 4 MB
  short* vt = (short*)(ws + (16ull << 20));     // 8 MB  [B,128,S]
  float* qmask = (float*)(ws + (24ull << 20));  // 128 KB
  float* kmask = (float*)(ws + (24ull << 20) + (size_t)B_N * S_N * 4);

  const int NB = B_N * S_N / 128;  // 256 blocks per projection
  proj_q_kernel<<<dim3(NB), 256, 0, stream>>>(queries_it, Wq_it, bq_it, qit, qmask);
  proj_k_mfma<<<dim3(NB), 256, 0, stream>>>(keys_it, Wk_it, bk_it, Wv, bv, kit, vt, kmask);
  proj_ctx2_kernel<<<dim3(2 * NB), 256, 0, stream>>>(
      queries_ctx, Wq_ctx, bq_ctx, qctx, keys_ctx, Wk_ctx, bk_ctx, kctx, NB);

  attn_kernel<<<dim3(B_N * (S_N / 64)), 256, 0, stream>>>(
      qit, kit, qctx, kctx, vt, noise, sigma, qmask, kmask, queries_it,
      W1, b1, W2, b2, out);
}